// Round 5
// baseline (20.898 us; speedup 1.0000x reference)
//
#include <hip/hip_runtime.h>

// BayesianDiffSizeCatEmbeddings: out[b, off_i : off_i+dim_i] =
//   mu_i[idx,:] + softplus(rho_i[idx,:]) * eps_i[idx,:],  idx = X[b,i]
// One thread = one 32 B pair of output float4s. Row = 62 quads = 31 pairs;
// all column boundaries are pair-aligned, so each pair lives in exactly one
// (column, table-row): branch-free decode, half the threads/X-loads/decode
// of the quad version, 6 outstanding gather loads per thread.

constexpr int BATCH = 16384;
constexpr int NCOLS = 8;
constexpr int PAIRS_PER_ROW = 31;                         // 248 floats / 8
constexpr unsigned TOTAL_PAIRS = BATCH * PAIRS_PER_ROW;   // 507,904
constexpr int TOTAL_BLOCKS = TOTAL_PAIRS / 256;           // 1984 (exact)

typedef float f4 __attribute__((ext_vector_type(4)));

struct Params {
    const float* mu[NCOLS];
    const float* rho[NCOLS];
    const float* eps[NCOLS];
    const int*   X;     // [BATCH, 8] int32
    float*       out;   // [BATCH, 248] f32
};

__device__ __forceinline__ float softplus_f(float x) {
    // jax.nn.softplus = log1p(exp(x)); rho ~ N(-6,0.1), guard for exactness.
    return (x > 15.0f) ? x : log1pf(__expf(x));
}

__device__ __forceinline__ f4 fuse4(f4 m, f4 r, f4 e) {
    f4 o;
    o.x = m.x + softplus_f(r.x) * e.x;
    o.y = m.y + softplus_f(r.y) * e.y;
    o.z = m.z + softplus_f(r.z) * e.z;
    o.w = m.w + softplus_f(r.w) * e.w;
    return o;
}

__global__ __launch_bounds__(256) void bayes_embed_pair(Params p) {
    const unsigned t = blockIdx.x * 256u + threadIdx.x;   // global pair id
    // b = t / 31 exactly (magic ceil(2^36/31), err 29: valid to t < 2.3e9)
    const unsigned b  = __umulhi(t, 2216757315u) >> 4;
    const unsigned pr = t - b * 31u;                      // pair within row, 0..30

    // pair-unit column boundaries: {0,8,16,20,24,26,28,30}
    const int ge8  = pr >= 8,  ge16 = pr >= 16, ge20 = pr >= 20, ge24 = pr >= 24,
              ge26 = pr >= 26, ge28 = pr >= 28, ge30 = pr >= 30;
    const int col = ge8 + ge16 + ge20 + ge24 + ge26 + ge28 + ge30;
    const unsigned pstart = ge30 ? 30u : ge28 ? 28u : ge26 ? 26u : ge24 ? 24u :
                            ge20 ? 20u : ge16 ? 16u : ge8 ? 8u : 0u;
    const int pshift = 3 - (ge16 + ge24 + ge30);          // log2(pairs per table row)
    const unsigned d  = pr - pstart;                      // pair within table row

    const int idx = p.X[b * NCOLS + col];

    // register select chain (block of cndmasks; keeps arrays out of scratch)
    const float* mu  = p.mu[0];
    const float* rho = p.rho[0];
    const float* eps = p.eps[0];
#pragma unroll
    for (int c = 1; c < NCOLS; ++c) {
        if (col == c) { mu = p.mu[c]; rho = p.rho[c]; eps = p.eps[c]; }
    }

    // element offset: idx*dim + d*8, dim = 8 << pshift; max 6.4e7 << 2^31
    const unsigned base = ((unsigned)idx << (pshift + 3)) + (d << 3);
    const f4 m0 = *(const f4*)(mu  + base);
    const f4 m1 = *(const f4*)(mu  + base + 4);
    const f4 r0 = *(const f4*)(rho + base);
    const f4 r1 = *(const f4*)(rho + base + 4);
    const f4 e0 = *(const f4*)(eps + base);
    const f4 e1 = *(const f4*)(eps + base + 4);

    const f4 o0 = fuse4(m0, r0, e0);
    const f4 o1 = fuse4(m1, r1, e1);

    // write-once output: nontemporal, address-linear across the grid
    float* op = p.out + (size_t)t * 8u;
    __builtin_nontemporal_store(o0, (f4*)op);
    __builtin_nontemporal_store(o1, (f4*)(op + 4));
}

extern "C" void kernel_launch(void* const* d_in, const int* in_sizes, int n_in,
                              void* d_out, int out_size, void* d_ws, size_t ws_size,
                              hipStream_t stream) {
    Params p;
    for (int i = 0; i < NCOLS; ++i) {
        p.mu[i]  = (const float*)d_in[3 * i + 0];
        p.rho[i] = (const float*)d_in[3 * i + 1];
        p.eps[i] = (const float*)d_in[3 * i + 2];
    }
    p.X   = (const int*)d_in[24];
    p.out = (float*)d_out;

    bayes_embed_pair<<<dim3(TOTAL_BLOCKS), 256, 0, stream>>>(p);
}